// Round 8
// baseline (494.005 us; speedup 1.0000x reference)
//
#include <hip/hip_runtime.h>

// GCN 2-layer. R8: XCD feature-sliced gathers — h stored slice-major
// (slice = 16 feats = 8 dwords); block b handles slice b%8 so each XCD's
// h working-set is 3.2MB (L2-resident). Wave = 8 edge-slots x 8 feat-dwords,
// 2-step unroll for MLP, cross-slot shfl reduction.
// Carry-over: bf16-MFMA GEMMs (operand-swap), bf16 storage, 15-bit weight
// (float bits[26:12]), atomic-free CSR, multi-block scan.

typedef unsigned int u32;
typedef unsigned short u16;
using bfrag = __attribute__((ext_vector_type(8))) short;
using f4    = __attribute__((ext_vector_type(4))) float;

__device__ inline u32 pack_bf16(float a, float b) {
    u32 ua = __float_as_uint(a);
    u32 ub = __float_as_uint(b);
    ua += 0x7fffu + ((ua >> 16) & 1u);   // RNE
    ub += 0x7fffu + ((ub >> 16) & 1u);
    return (ua >> 16) | (ub & 0xffff0000u);
}
__device__ inline float bf_lo(u32 v) { return __uint_as_float(v << 16); }
__device__ inline float bf_hi(u32 v) { return __uint_as_float(v & 0xffff0000u); }

// w in [2^-15, 2): store float bits[26:12]. Decode = shl+or.
__device__ inline u32 pack_w(float w) {
    u32 b = __float_as_uint(w) + 0x800u;
    if (b < 0x38000000u) b = 0x38000000u;
    return (b >> 12) & 0x7fffu;
}
__device__ inline float dec_w(u32 e) {
    return __uint_as_float(0x38000000u | ((e & 0x7fffu) << 12));
}

__device__ inline bfrag as_bfrag(uint4 v) {
    union { uint4 u; bfrag b; } x; x.u = v; return x.b;
}

__global__ void zero_i32(int* __restrict__ p, int n) {
    int i = blockIdx.x * blockDim.x + threadIdx.x;
    if (i < n) p[i] = 0;
}

__global__ void hist_rank(const int* __restrict__ dst, int* __restrict__ cnt,
                          int* __restrict__ rank, int E) {
    int e = blockIdx.x * blockDim.x + threadIdx.x;
    if (e < E) rank[e] = atomicAdd(&cnt[dst[e]], 1);
}

__global__ __launch_bounds__(1024) void scan_reduce(const int* __restrict__ cnt,
                                                    int* __restrict__ bsum, int n) {
    __shared__ int wsum[16];
    int i = blockIdx.x * 1024 + threadIdx.x;
    int v = (i < n) ? cnt[i] : 0;
#pragma unroll
    for (int off = 32; off > 0; off >>= 1) v += __shfl_down(v, off);
    const int lane = threadIdx.x & 63;
    const int wid  = threadIdx.x >> 6;
    if (lane == 0) wsum[wid] = v;
    __syncthreads();
    if (threadIdx.x < 16) {
        int s = wsum[threadIdx.x];
#pragma unroll
        for (int off = 8; off > 0; off >>= 1) s += __shfl_down(s, off);
        if (threadIdx.x == 0) bsum[blockIdx.x] = s;
    }
}

__global__ void scan_partials(const int* __restrict__ bsum, int* __restrict__ boff,
                              int* __restrict__ row_ptr, int nb, int n) {
    const int lane = threadIdx.x;  // 64 threads
    int carry = 0;
    for (int base = 0; base < nb; base += 64) {
        int i = base + lane;
        int v = (i < nb) ? bsum[i] : 0;
        int x = v;
#pragma unroll
        for (int off = 1; off < 64; off <<= 1) {
            int t = __shfl_up(x, off);
            if (lane >= off) x += t;
        }
        if (i < nb) boff[i] = carry + x - v;
        carry += __shfl(x, 63);
    }
    if (lane == 0) row_ptr[n] = carry;
}

__global__ __launch_bounds__(1024) void scan_apply(const int* __restrict__ cnt,
                                                   const int* __restrict__ boff,
                                                   int* __restrict__ row_ptr,
                                                   float* __restrict__ dinv, int n) {
    __shared__ int wsum[16];
    const int lane = threadIdx.x & 63;
    const int wid  = threadIdx.x >> 6;
    int i = blockIdx.x * 1024 + threadIdx.x;
    int v = (i < n) ? cnt[i] : 0;
    int x = v;
#pragma unroll
    for (int off = 1; off < 64; off <<= 1) {
        int t = __shfl_up(x, off);
        if (lane >= off) x += t;
    }
    if (lane == 63) wsum[wid] = x;
    __syncthreads();
    if (wid == 0 && lane < 16) {
        int w = wsum[lane];
#pragma unroll
        for (int off = 1; off < 16; off <<= 1) {
            int t = __shfl_up(w, off);
            if (lane >= off) w += t;
        }
        wsum[lane] = w;
    }
    __syncthreads();
    int wave_excl = (wid == 0) ? 0 : wsum[wid - 1];
    if (i < n) {
        row_ptr[i] = boff[blockIdx.x] + wave_excl + (x - v);
        dinv[i]    = rsqrtf((float)v + 1.0f);
    }
}

__global__ void place_csr(const int* __restrict__ src, const int* __restrict__ dst,
                          const int* __restrict__ rank, const int* __restrict__ row_ptr,
                          const float* __restrict__ dinv, u32* __restrict__ ew, int E) {
    int e = blockIdx.x * blockDim.x + threadIdx.x;
    if (e < E) {
        int s = src[e];
        int d = dst[e];
        float w = dinv[s] * dinv[d];
        ew[row_ptr[d] + rank[e]] = ((u32)s << 15) | pack_w(w);
    }
}

__global__ void prep_w(const float* __restrict__ W1, const float* __restrict__ W2,
                       u32* __restrict__ W1t, u32* __restrict__ W2t) {
    int idx = blockIdx.x * 256 + threadIdx.x;
    if (idx < 128 * 64) {
        int nr = idx >> 6, kd = idx & 63;
        W1t[idx] = pack_bf16(W1[(2 * kd) * 128 + nr], W1[(2 * kd + 1) * 128 + nr]);
    } else if (idx < 128 * 64 + 64 * 64) {
        int i = idx - 128 * 64;
        int nr = i >> 6, kd = i & 63;
        W2t[i] = pack_bf16(W2[(2 * kd) * 64 + nr], W2[(2 * kd + 1) * 64 + nr]);
    }
}

// C = A @ W via 16x16x32 bf16 MFMA (operand swap).
// Output: slice-major bf16: C[(slice*n + row)*8 + dword], slice = 16 cols.
// ASLICED: A is slice-major bf16 (8 slices over K=128); else fp32 row-major.
template <int OUT, bool ASLICED>
__global__ __launch_bounds__(256) void gemm_mfma(const void* __restrict__ Ap,
                                                 const u32* __restrict__ Wt,
                                                 u32* __restrict__ C, int n) {
    constexpr int NT = OUT / 16;
    const int lane = threadIdx.x & 63;
    const int wv   = threadIdx.x >> 6;
    const int r15  = lane & 15;
    const int quad = lane >> 4;
    const int rowbase = blockIdx.x * 128 + wv * 32;

    bfrag af[2][4];
#pragma unroll
    for (int mi = 0; mi < 2; ++mi) {
        int row = rowbase + mi * 16 + r15;
        row = (row < n) ? row : (n - 1);
        if constexpr (ASLICED) {
            const u32* ab = (const u32*)Ap;
#pragma unroll
            for (int ks = 0; ks < 4; ++ks) {
                int slice = ks * 2 + (quad >> 1);
                const u32* ar = ab + ((size_t)slice * n + row) * 8 + (quad & 1) * 4;
                af[mi][ks] = as_bfrag(*(const uint4*)ar);
            }
        } else {
            const float* arf = (const float*)Ap + (size_t)row * 128 + quad * 8;
#pragma unroll
            for (int ks = 0; ks < 4; ++ks) {
                float4 v0 = *(const float4*)(arf + ks * 32);
                float4 v1 = *(const float4*)(arf + ks * 32 + 4);
                uint4 p;
                p.x = pack_bf16(v0.x, v0.y);
                p.y = pack_bf16(v0.z, v0.w);
                p.z = pack_bf16(v1.x, v1.y);
                p.w = pack_bf16(v1.z, v1.w);
                af[mi][ks] = as_bfrag(p);
            }
        }
    }

    f4 acc[2][NT];
#pragma unroll
    for (int mi = 0; mi < 2; ++mi)
#pragma unroll
        for (int nt = 0; nt < NT; ++nt) acc[mi][nt] = (f4)0.0f;

#pragma unroll
    for (int nt = 0; nt < NT; ++nt) {
        const u32* wr = Wt + (size_t)(nt * 16 + r15) * 64 + quad * 4;
#pragma unroll
        for (int ks = 0; ks < 4; ++ks) {
            bfrag bf = as_bfrag(*(const uint4*)(wr + ks * 16));
            acc[0][nt] = __builtin_amdgcn_mfma_f32_16x16x32_bf16(bf, af[0][ks], acc[0][nt], 0, 0, 0);
            acc[1][nt] = __builtin_amdgcn_mfma_f32_16x16x32_bf16(bf, af[1][ks], acc[1][nt], 0, 0, 0);
        }
    }

    // store: slice nt, dwords quad*2, quad*2+1
#pragma unroll
    for (int mi = 0; mi < 2; ++mi) {
        int row = rowbase + mi * 16 + r15;
        if (row < n) {
#pragma unroll
            for (int nt = 0; nt < NT; ++nt) {
                uint2 p;
                p.x = pack_bf16(acc[mi][nt][0], acc[mi][nt][1]);
                p.y = pack_bf16(acc[mi][nt][2], acc[mi][nt][3]);
                *(uint2*)(C + ((size_t)nt * n + row) * 8 + quad * 2) = p;
            }
        }
    }
}

// Layer-1 gather, XCD-sliced: slice g = blockIdx%8 (16 feats). Wave = 8 edge
// slots x 8 feat-dwords. Output agg1 slice-major bf16 (relu'd).
__global__ __launch_bounds__(256) void gather128s(const u32* __restrict__ hs,
                                                  const float* __restrict__ dinv,
                                                  const int* __restrict__ row_ptr,
                                                  const u32* __restrict__ ew,
                                                  const float* __restrict__ bias,
                                                  u32* __restrict__ outs, int n) {
    const int lane = threadIdx.x & 63;
    const int fd   = lane & 7;
    const int sub  = lane >> 3;
    const int g    = blockIdx.x & 7;
    const int wv   = (blockIdx.x >> 3) * 4 + (threadIdx.x >> 6);
    const int nwv  = (gridDim.x >> 3) * 4;
    const u32* hg  = hs + (size_t)g * n * 8;
    const float2 bb = ((const float2*)bias)[g * 8 + fd];

    for (int node = wv; node < n; node += nwv) {
        const int beg = row_ptr[node];
        const int end = row_ptr[node + 1];
        float acc0 = 0.0f, acc1 = 0.0f;
        for (int base = beg; base < end; base += 16) {
            int i0 = base + sub;
            int i1 = base + 8 + sub;
            u32 e0 = ew[(i0 < end) ? i0 : (end - 1)];
            u32 e1 = ew[(i1 < end) ? i1 : (end - 1)];
            float w0 = (i0 < end) ? dec_w(e0) : 0.0f;
            float w1 = (i1 < end) ? dec_w(e1) : 0.0f;
            u32 v0 = hg[(e0 >> 15) * 8u + fd];
            u32 v1 = hg[(e1 >> 15) * 8u + fd];
            acc0 = fmaf(w0, bf_lo(v0), acc0); acc1 = fmaf(w0, bf_hi(v0), acc1);
            acc0 = fmaf(w1, bf_lo(v1), acc0); acc1 = fmaf(w1, bf_hi(v1), acc1);
        }
        // reduce over 8 edge slots (lane bits 3..5)
        acc0 += __shfl_xor(acc0, 8);  acc1 += __shfl_xor(acc1, 8);
        acc0 += __shfl_xor(acc0, 16); acc1 += __shfl_xor(acc1, 16);
        acc0 += __shfl_xor(acc0, 32); acc1 += __shfl_xor(acc1, 32);
        if (sub == 0) {
            float dd = dinv[node];
            u32 sv = hg[(u32)node * 8u + fd];
            float r0 = fmaf(bf_lo(sv) * dd, dd, acc0 + bb.x);
            float r1 = fmaf(bf_hi(sv) * dd, dd, acc1 + bb.y);
            outs[((size_t)g * n + node) * 8 + fd] =
                pack_bf16(fmaxf(r0, 0.0f), fmaxf(r1, 0.0f));
        }
    }
}

// Layer-2 gather, XCD-sliced: 4 slices, 2 XCD-groups each. fp32 out (row-major).
__global__ __launch_bounds__(256) void gather64s(const u32* __restrict__ hs,
                                                 const float* __restrict__ dinv,
                                                 const int* __restrict__ row_ptr,
                                                 const u32* __restrict__ ew,
                                                 const float* __restrict__ bias,
                                                 float* __restrict__ outp, int n) {
    const int lane = threadIdx.x & 63;
    const int fd   = lane & 7;
    const int sub  = lane >> 3;
    const int g    = (blockIdx.x & 7) >> 1;
    const int wv   = ((blockIdx.x >> 3) * 2 + (blockIdx.x & 1)) * 4 + (threadIdx.x >> 6);
    const int nwv  = (gridDim.x >> 3) * 8;
    const u32* hg  = hs + (size_t)g * n * 8;
    const float2 bb = ((const float2*)bias)[g * 8 + fd];

    for (int node = wv; node < n; node += nwv) {
        const int beg = row_ptr[node];
        const int end = row_ptr[node + 1];
        float acc0 = 0.0f, acc1 = 0.0f;
        for (int base = beg; base < end; base += 16) {
            int i0 = base + sub;
            int i1 = base + 8 + sub;
            u32 e0 = ew[(i0 < end) ? i0 : (end - 1)];
            u32 e1 = ew[(i1 < end) ? i1 : (end - 1)];
            float w0 = (i0 < end) ? dec_w(e0) : 0.0f;
            float w1 = (i1 < end) ? dec_w(e1) : 0.0f;
            u32 v0 = hg[(e0 >> 15) * 8u + fd];
            u32 v1 = hg[(e1 >> 15) * 8u + fd];
            acc0 = fmaf(w0, bf_lo(v0), acc0); acc1 = fmaf(w0, bf_hi(v0), acc1);
            acc0 = fmaf(w1, bf_lo(v1), acc0); acc1 = fmaf(w1, bf_hi(v1), acc1);
        }
        acc0 += __shfl_xor(acc0, 8);  acc1 += __shfl_xor(acc1, 8);
        acc0 += __shfl_xor(acc0, 16); acc1 += __shfl_xor(acc1, 16);
        acc0 += __shfl_xor(acc0, 32); acc1 += __shfl_xor(acc1, 32);
        if (sub == 0) {
            float dd = dinv[node];
            u32 sv = hg[(u32)node * 8u + fd];
            float r0 = fmaf(bf_lo(sv) * dd, dd, acc0 + bb.x);
            float r1 = fmaf(bf_hi(sv) * dd, dd, acc1 + bb.y);
            ((float2*)outp)[(u32)node * 32u + g * 8u + fd] = make_float2(r0, r1);
        }
    }
}

extern "C" void kernel_launch(void* const* d_in, const int* in_sizes, int n_in,
                              void* d_out, int out_size, void* d_ws, size_t ws_size,
                              hipStream_t stream) {
    const float* x  = (const float*)d_in[0];
    const int*   ei = (const int*)d_in[1];
    const float* W1 = (const float*)d_in[2];
    const float* b1 = (const float*)d_in[3];
    const float* W2 = (const float*)d_in[4];
    const float* b2 = (const float*)d_in[5];
    float*       out = (float*)d_out;

    const int n = in_sizes[0] / 128;   // 100000
    const int E = in_sizes[1] / 2;     // 1600000
    const int* srcv = ei;
    const int* dstv = ei + E;

    const int NP = 102400;
    u32* wsd = (u32*)d_ws;
    float* dinv    = (float*)wsd;                        // NP
    int*   row_ptr = (int*)(wsd + NP);                   // NP
    u32*   ew      = wsd + 2 * (size_t)NP;               // E
    u32*   h1s     = ew + E;                             // n*64 (sliced, 8 slices)
    u32*   agg1s   = h1s + (size_t)n * 64;               // n*64 (sliced, 8 slices)
    u32*   W1t     = agg1s + (size_t)n * 64;             // 8192
    u32*   W2t     = W1t + 8192;                         // 4096
    int*   bsum    = (int*)(W2t + 4096);                 // 128
    int*   boff    = bsum + 128;                         // 128
    u32*   h2s     = h1s;                                // n*32 (sliced, 4 slices)
    int*   cnt     = (int*)h1s;    // overlay: dead before gemm1 writes
    int*   rank    = (int*)agg1s;  // overlay: dead before gather128 writes

    const int NB = (n + 1023) / 1024;

    // --- CSR build ---
    zero_i32<<<(n + 255) / 256, 256, 0, stream>>>(cnt, n);
    hist_rank<<<(E + 255) / 256, 256, 0, stream>>>(dstv, cnt, rank, E);
    scan_reduce<<<NB, 1024, 0, stream>>>(cnt, bsum, n);
    scan_partials<<<1, 64, 0, stream>>>(bsum, boff, row_ptr, NB, n);
    scan_apply<<<NB, 1024, 0, stream>>>(cnt, boff, row_ptr, dinv, n);
    place_csr<<<(E + 255) / 256, 256, 0, stream>>>(srcv, dstv, rank, row_ptr, dinv, ew, E);

    // --- weights to bf16, transposed ---
    prep_w<<<48, 256, 0, stream>>>(W1, W2, W1t, W2t);

    const int gblocks = (n + 127) / 128;  // 782
    // --- layer 1 ---
    gemm_mfma<128, false><<<gblocks, 256, 0, stream>>>(x, W1t, h1s, n);
    gather128s<<<2048, 256, 0, stream>>>(h1s, dinv, row_ptr, ew, b1, agg1s, n);

    // --- layer 2 ---
    gemm_mfma<64, true><<<gblocks, 256, 0, stream>>>(agg1s, W2t, h2s, n);
    gather64s<<<2048, 256, 0, stream>>>(h2s, dinv, row_ptr, ew, b2, out, n);
}